// Round 1
// baseline (201.586 us; speedup 1.0000x reference)
//
#include <hip/hip_runtime.h>
#include <math.h>

// Gent hyperelastic energy, elementwise over (N,3,3) float32 inputs.
// E=75000, NU=0.3, JM=100  ->  G = E/(2(1+nu)) = 28846.1538..., K = E/(3(1-2nu)) = 62500.
// Memory-bound: 36 B in + 4 B out per element. LDS-staged float4 global loads.

#define ELEMS_PER_BLOCK 256

__global__ __launch_bounds__(256) void gent_kernel(const float* __restrict__ x,
                                                   float* __restrict__ out,
                                                   int n) {
    __shared__ float s[ELEMS_PER_BLOCK * 9];  // 9216 B
    const int tid = threadIdx.x;
    const long long base_elem = (long long)blockIdx.x * ELEMS_PER_BLOCK;
    int m = n - (int)base_elem;
    if (m > ELEMS_PER_BLOCK) m = ELEMS_PER_BLOCK;

    if (m == ELEMS_PER_BLOCK) {
        // 256 elems * 9 floats = 2304 floats = 576 float4; block base byte
        // offset = blockIdx.x * 9216, 16B-aligned -> legal float4 loads.
        const float4* __restrict__ g4 = (const float4*)(x + base_elem * 9);
        float4* s4 = (float4*)s;
        s4[tid]       = g4[tid];
        s4[tid + 256] = g4[tid + 256];
        if (tid < 64) s4[tid + 512] = g4[tid + 512];
    } else {
        const int nf = m * 9;
        const float* __restrict__ g = x + base_elem * 9;
        for (int k = tid; k < nf; k += ELEMS_PER_BLOCK) s[k] = g[k];
    }
    __syncthreads();

    if (tid < m) {
        // stride-9 dwords across lanes: 9 coprime with 32 banks -> conflict-free
        const float* f = s + tid * 9;
        const float a = f[0], b = f[1], c = f[2];
        const float d = f[3], e = f[4], g = f[5];
        const float h = f[6], i = f[7], j = f[8];

        // I1 = tr(F^T F) = sum of squares
        const float I1 = a*a + b*b + c*c + d*d + e*e + g*g + h*h + i*i + j*j;
        // J = det(F)
        const float J = a*(e*j - g*i) - b*(d*j - g*h) + c*(d*i - e*h);

        const float Jm23  = 1.0f / cbrtf(J * J);      // J^(-2/3)
        const float I1bar = I1 * Jm23;
        const float vol   = 0.5f * (J*J - 1.0f) - logf(J);
        const float v2    = vol * vol;

        // -G/2*JM = -28846.153846... * 50 ;  K/2 = 31250
        const float w = (-0.5f * 28846.153846153848f * 100.0f)
                          * logf(1.0f - (I1bar - 3.0f) * 0.01f)
                      + 31250.0f * v2 * v2;

        out[base_elem + tid] = w;
    }
}

extern "C" void kernel_launch(void* const* d_in, const int* in_sizes, int n_in,
                              void* d_out, int out_size, void* d_ws, size_t ws_size,
                              hipStream_t stream) {
    const float* x = (const float*)d_in[0];
    float* out = (float*)d_out;
    const int n = in_sizes[0] / 9;  // number of 3x3 matrices
    const int grid = (n + ELEMS_PER_BLOCK - 1) / ELEMS_PER_BLOCK;
    gent_kernel<<<grid, ELEMS_PER_BLOCK, 0, stream>>>(x, out, n);
}